// Round 3
// baseline (134.608 us; speedup 1.0000x reference)
//
#include <hip/hip_runtime.h>
#include <hip/hip_bf16.h>

// Problem constants (fixed by the reference's setup_inputs)
#define BB 8
#define HH 16
#define SS 1024
#define KK 10          // NUM_TOP
#define NL 8           // num_labels
#define FF (HH * KK)   // 160 features
#define NCHUNK 8       // row chunks (one wave each)
#define RPC (SS / NCHUNK)   // 128 rows per chunk

#define NEG_FLT_MAX (-3.402823466e+38f)

// Unconditional sorted-descending top-10 insertion. k descends so a[k-1] is
// still the OLD value when a[k] is computed. Fully unrolled -> static indices
// -> stays in VGPRs (no scratch).
__device__ __forceinline__ void topk_insert(float (&a)[KK], float v) {
#pragma unroll
    for (int k = KK - 1; k >= 1; --k)
        a[k] = fminf(fmaxf(v, a[k]), a[k - 1]);
    a[0] = fmaxf(a[0], v);
}

// Block = 512 threads = 8 waves. Block owns 256 consecutive columns of one
// (b,h) matrix; wave w scans rows [w*128, w*128+128). Lane l -> columns
// 4l..4l+3 via float4 loads: 1KB per wave-instruction, coalesced.
// 512 blocks = 2 blocks/CU; launch_bounds(512,4) -> <=128 VGPR -> 4 waves/SIMD.
__global__ __launch_bounds__(512, 4) void topk_kernel(
        const float* __restrict__ att, float* __restrict__ feats) {
    // [src][k][j][lane] with col = 4*lane + j  -> conflict-free read & write
    __shared__ float lds[4][KK][4][64];

    const int lane = threadIdx.x & 63;
    const int w    = threadIdx.x >> 6;           // wave index = row chunk
    const int bh   = blockIdx.x >> 2;            // 4 col-groups per (b,h)
    const int cg   = blockIdx.x & 3;
    const int colbase = (cg << 8) + (lane << 2); // this lane's first column

    const float* p = att + (size_t)bh * SS * SS
                         + (size_t)(w * RPC) * SS + colbase;

    float a[4][KK];
#pragma unroll
    for (int c = 0; c < 4; ++c)
#pragma unroll
        for (int k = 0; k < KK; ++k) a[c][k] = NEG_FLT_MAX;

    for (int j = 0; j < RPC; j += 8) {
        float4 v[8];
#pragma unroll
        for (int r = 0; r < 8; ++r)
            v[r] = *(const float4*)(p + (size_t)(j + r) * SS);
#pragma unroll
        for (int r = 0; r < 8; ++r) {
            topk_insert(a[0], v[r].x);
            topk_insert(a[1], v[r].y);
            topk_insert(a[2], v[r].z);
            topk_insert(a[3], v[r].w);
        }
    }

    // Stage 1: waves 4..7 publish partials; waves 0..3 fold chunk w+4.
    if (w >= 4) {
#pragma unroll
        for (int k = 0; k < KK; ++k)
#pragma unroll
            for (int c = 0; c < 4; ++c)
                lds[w - 4][k][c][lane] = a[c][k];
    }
    __syncthreads();
    if (w < 4) {
#pragma unroll
        for (int k = 0; k < KK; ++k)
#pragma unroll
            for (int c = 0; c < 4; ++c)
                topk_insert(a[c], lds[w][k][c][lane]);
    }
    __syncthreads();
    // Stage 2: waves 1..3 publish merged partials; wave 0 folds all three.
    if (w >= 1 && w < 4) {
#pragma unroll
        for (int k = 0; k < KK; ++k)
#pragma unroll
            for (int c = 0; c < 4; ++c)
                lds[w - 1][k][c][lane] = a[c][k];
    }
    __syncthreads();
    if (w == 0) {
#pragma unroll
        for (int src = 0; src < 3; ++src)
#pragma unroll
            for (int k = 0; k < KK; ++k)
#pragma unroll
                for (int c = 0; c < 4; ++c)
                    topk_insert(a[c], lds[src][k][c][lane]);

        const int b = bh >> 4;          // H = 16
        const int h = bh & (HH - 1);
#pragma unroll
        for (int c = 0; c < 4; ++c) {
            const int col = colbase + c;
            float* o = feats + ((size_t)(b * SS + col) * HH + h) * KK;
#pragma unroll
            for (int k = 0; k < KK; ++k) o[k] = a[c][k];
        }
    }
}

// Tiny linear layer: one thread per (b, s). W cached in LDS (broadcast reads).
__global__ __launch_bounds__(256) void linear_kernel(
        const float* __restrict__ feats, const float* __restrict__ W,
        const float* __restrict__ bias, float* __restrict__ out) {
    __shared__ float sW[NL * FF];
    __shared__ float sb[NL];
    for (int i = threadIdx.x; i < NL * FF; i += 256) sW[i] = W[i];
    if (threadIdx.x < NL) sb[threadIdx.x] = bias[threadIdx.x];
    __syncthreads();

    const int t = blockIdx.x * 256 + threadIdx.x;   // 0 .. B*S-1

    const float4* f4 = (const float4*)(feats + (size_t)t * FF);
    float acc[NL];
#pragma unroll
    for (int l = 0; l < NL; ++l) acc[l] = sb[l];

#pragma unroll 4
    for (int i = 0; i < FF / 4; ++i) {
        const float4 v = f4[i];
#pragma unroll
        for (int l = 0; l < NL; ++l) {
            const float* w = &sW[l * FF + i * 4];
            acc[l] += v.x * w[0] + v.y * w[1] + v.z * w[2] + v.w * w[3];
        }
    }

    float4* o4 = (float4*)(out + (size_t)t * NL);
    o4[0] = make_float4(acc[0], acc[1], acc[2], acc[3]);
    o4[1] = make_float4(acc[4], acc[5], acc[6], acc[7]);
}

extern "C" void kernel_launch(void* const* d_in, const int* in_sizes, int n_in,
                              void* d_out, int out_size, void* d_ws, size_t ws_size,
                              hipStream_t stream) {
    const float* att  = (const float*)d_in[0];   // (B,H,S,S) fp32
    const float* W    = (const float*)d_in[1];   // (8,160)   fp32
    const float* bias = (const float*)d_in[2];   // (8,)      fp32
    float* out   = (float*)d_out;                // (B,S,8)   fp32
    float* feats = (float*)d_ws;                 // needs B*S*160*4 = 5.25 MB

    topk_kernel<<<(BB * HH) * 4, 512, 0, stream>>>(att, feats);
    linear_kernel<<<(BB * SS) / 256, 256, 0, stream>>>(feats, W, bias, out);
}

// Round 4
// 119.070 us; speedup vs baseline: 1.1305x; 1.1305x over previous
//
#include <hip/hip_runtime.h>
#include <hip/hip_bf16.h>

// Problem constants (fixed by the reference's setup_inputs)
#define BB 8
#define HH 16
#define SS 1024
#define KK 10          // NUM_TOP
#define NL 8           // num_labels
#define FF (HH * KK)   // 160 features
#define NCHUNK 4       // row chunks per column (one wave each)
#define RPC (SS / NCHUNK)   // 256 rows per chunk

#define NEG_FLT_MAX (-3.402823466e+38f)

// Sorted-descending top-10 insertion, one v_med3_f32 per stage:
//   new_a[k] = min(max(v, a[k]), a[k-1]) == med3(v, a[k], a[k-1])
// (valid because a[k] <= a[k-1]).  All 10 stage-ops read only OLD values
// (k descending), so they are mutually independent -> ~4-cycle dep per insert.
// Fully unrolled -> static indices -> stays in VGPRs.
__device__ __forceinline__ void topk_insert(float (&a)[KK], float v) {
#pragma unroll
    for (int k = KK - 1; k >= 1; --k)
        a[k] = __builtin_amdgcn_fmed3f(v, a[k], a[k - 1]);
    a[0] = fmaxf(a[0], v);
}

// Block = 256 threads = 4 waves. Block owns 64 consecutive columns of one
// (b,h) matrix; wave w scans rows [w*256, w*256+256) (lane -> column,
// coalesced 256B/wave row reads). Partials merged through LDS by wave 0.
// 2048 blocks = 8 blocks/CU = 8 waves/SIMD; ~40 VGPR -> no cap needed.
__global__ __launch_bounds__(256) void topk_kernel(
        const float* __restrict__ att, float* __restrict__ feats) {
    __shared__ float lds[NCHUNK][KK][64];

    const int lane = threadIdx.x & 63;
    const int w    = threadIdx.x >> 6;           // wave index = row chunk
    const int bh   = blockIdx.x >> 4;            // 16 blocks per (b,h)
    const int col  = ((blockIdx.x & 15) << 6) + lane;

    const float* p = att + (size_t)bh * SS * SS
                         + (size_t)(w * RPC) * SS + col;

    float a[KK];
#pragma unroll
    for (int k = 0; k < KK; ++k) a[k] = NEG_FLT_MAX;

    for (int j = 0; j < RPC; j += 16) {
        const float* q = p + (size_t)j * SS;
        float v[16];
        // 16 independent scalar loads in flight (~16 VGPRs), then 16 inserts
#pragma unroll
        for (int r = 0; r < 16; ++r)
            v[r] = q[(size_t)r * SS];
#pragma unroll
        for (int r = 0; r < 16; ++r)
            topk_insert(a, v[r]);
    }

    // Publish partial top-10 (lane-contiguous -> conflict-free)
#pragma unroll
    for (int k = 0; k < KK; ++k) lds[w][k][lane] = a[k];
    __syncthreads();

    if (w == 0) {
        // a[] already holds chunk 0's list; fold in chunks 1..3.
#pragma unroll
        for (int c = 1; c < NCHUNK; ++c)
#pragma unroll
            for (int k = 0; k < KK; ++k)
                topk_insert(a, lds[c][k][lane]);

        const int b = bh >> 4;          // H = 16
        const int h = bh & (HH - 1);
        float* o = feats + ((size_t)(b * SS + col) * HH + h) * KK;
#pragma unroll
        for (int k = 0; k < KK; ++k) o[k] = a[k];
    }
}

// Tiny linear layer: one thread per (b, s). W cached in LDS (broadcast reads).
__global__ __launch_bounds__(256) void linear_kernel(
        const float* __restrict__ feats, const float* __restrict__ W,
        const float* __restrict__ bias, float* __restrict__ out) {
    __shared__ float sW[NL * FF];
    __shared__ float sb[NL];
    for (int i = threadIdx.x; i < NL * FF; i += 256) sW[i] = W[i];
    if (threadIdx.x < NL) sb[threadIdx.x] = bias[threadIdx.x];
    __syncthreads();

    const int t = blockIdx.x * 256 + threadIdx.x;   // 0 .. B*S-1

    const float4* f4 = (const float4*)(feats + (size_t)t * FF);
    float acc[NL];
#pragma unroll
    for (int l = 0; l < NL; ++l) acc[l] = sb[l];

#pragma unroll 4
    for (int i = 0; i < FF / 4; ++i) {
        const float4 v = f4[i];
#pragma unroll
        for (int l = 0; l < NL; ++l) {
            const float* w = &sW[l * FF + i * 4];
            acc[l] += v.x * w[0] + v.y * w[1] + v.z * w[2] + v.w * w[3];
        }
    }

    float4* o4 = (float4*)(out + (size_t)t * NL);
    o4[0] = make_float4(acc[0], acc[1], acc[2], acc[3]);
    o4[1] = make_float4(acc[4], acc[5], acc[6], acc[7]);
}

extern "C" void kernel_launch(void* const* d_in, const int* in_sizes, int n_in,
                              void* d_out, int out_size, void* d_ws, size_t ws_size,
                              hipStream_t stream) {
    const float* att  = (const float*)d_in[0];   // (B,H,S,S) fp32
    const float* W    = (const float*)d_in[1];   // (8,160)   fp32
    const float* bias = (const float*)d_in[2];   // (8,)      fp32
    float* out   = (float*)d_out;                // (B,S,8)   fp32
    float* feats = (float*)d_ws;                 // needs B*S*160*4 = 5.25 MB

    topk_kernel<<<(BB * HH * SS) / 64, 256, 0, stream>>>(att, feats);
    linear_kernel<<<(BB * SS) / 256, 256, 0, stream>>>(feats, W, bias, out);
}

// Round 5
// 110.181 us; speedup vs baseline: 1.2217x; 1.0807x over previous
//
#include <hip/hip_runtime.h>
#include <hip/hip_bf16.h>

// Problem constants (fixed by the reference's setup_inputs)
#define BB 8
#define HH 16
#define SS 1024
#define KK 10          // NUM_TOP
#define NL 8           // num_labels
#define FF (HH * KK)   // 160 features
#define NQ 4           // row quarters (cross-block split)
#define RPQ (SS / NQ)  // 256 rows per quarter

#define NEG_FLT_MAX (-3.402823466e+38f)

// Workspace layout (primary path):
//   [0, 20971520)            partial[bh][q][k][col]  128*4*10*1024 floats
//   [20971520, 26214400)     feats[b][s][h][k]       8*1024*160 floats
#define PARTIAL_BYTES (128u * NQ * KK * SS * 4u)      // 20,971,520
#define FEATS_OFF_F   (128u * NQ * KK * SS)           // float offset
#define TOTAL_WS_BYTES (PARTIAL_BYTES + (BB * SS * FF * 4u))

// Sorted-descending top-10 insertion, one v_med3_f32 per stage:
//   new_a[k] = min(max(v, a[k]), a[k-1]) == med3(v, a[k], a[k-1])  (a[k]<=a[k-1])
// k descends so a[k-1] is the OLD value; stages mutually independent.
__device__ __forceinline__ void topk_insert(float (&a)[KK], float v) {
#pragma unroll
    for (int k = KK - 1; k >= 1; --k)
        a[k] = __builtin_amdgcn_fmed3f(v, a[k], a[k - 1]);
    a[0] = fmaxf(a[0], v);
}

// ---------------- primary path: block-sequential streaming ----------------
// Block = 256 threads = 4 waves, owns (bh, quarter): rows [q*256, q*256+256),
// ALL 1024 columns. Thread t keeps 4 lists for cols {t, t+256, t+512, t+768};
// per row the block's 16 wave-loads cover one contiguous 4KB row, and the
// block streams a contiguous 1MB region -> DRAM page-friendly. 512 blocks.
__global__ __launch_bounds__(256) void topk_partial_kernel(
        const float* __restrict__ att, float* __restrict__ partial) {
    const int t  = threadIdx.x;
    const int bh = blockIdx.x >> 2;
    const int q  = blockIdx.x & 3;

    const float* base = att + (size_t)bh * SS * SS + (size_t)q * RPQ * SS + t;

    float a[4][KK];
#pragma unroll
    for (int c = 0; c < 4; ++c)
#pragma unroll
        for (int k = 0; k < KK; ++k) a[c][k] = NEG_FLT_MAX;

    for (int r = 0; r < RPQ; r += 4) {
        float v[4][4];
#pragma unroll
        for (int i = 0; i < 4; ++i) {
            const float* p = base + (size_t)(r + i) * SS;
            // 4 loads share one vaddr via 13-bit imm offsets (0..3072B)
            v[i][0] = __builtin_nontemporal_load(p);
            v[i][1] = __builtin_nontemporal_load(p + 256);
            v[i][2] = __builtin_nontemporal_load(p + 512);
            v[i][3] = __builtin_nontemporal_load(p + 768);
        }
#pragma unroll
        for (int i = 0; i < 4; ++i) {
            topk_insert(a[0], v[i][0]);
            topk_insert(a[1], v[i][1]);
            topk_insert(a[2], v[i][2]);
            topk_insert(a[3], v[i][3]);
        }
    }

    // partial[bh][q][k][col]: per (k,c) a wave writes 256B contiguous
    float* o = partial + ((size_t)(bh * NQ + q) * KK) * SS;
#pragma unroll
    for (int k = 0; k < KK; ++k)
#pragma unroll
        for (int c = 0; c < 4; ++c)
            o[(size_t)k * SS + (c << 8) + t] = a[c][k];
}

// Merge 4 partial lists per (bh,col) -> feats. Fully coalesced reads.
__global__ __launch_bounds__(256) void topk_merge_kernel(
        const float* __restrict__ partial, float* __restrict__ feats) {
    const int g   = blockIdx.x * 256 + threadIdx.x;  // 0 .. 128*1024-1
    const int bh  = g >> 10;
    const int col = g & (SS - 1);

    const float* p = partial + (size_t)bh * NQ * KK * SS + col;

    float a[KK];
#pragma unroll
    for (int k = 0; k < KK; ++k) a[k] = p[(size_t)k * SS];
#pragma unroll
    for (int q = 1; q < NQ; ++q)
#pragma unroll
        for (int k = 0; k < KK; ++k)
            topk_insert(a, p[((size_t)q * KK + k) * SS]);

    const int b = bh >> 4;          // H = 16
    const int h = bh & (HH - 1);
    float* o = feats + ((size_t)(b * SS + col) * HH + h) * KK;
#pragma unroll
    for (int k = 0; k < KK; ++k) o[k] = a[k];
}

// ---------------- fallback path (proven R3): in-block merge ----------------
__global__ __launch_bounds__(256) void topk_kernel_fb(
        const float* __restrict__ att, float* __restrict__ feats) {
    __shared__ float lds[4][KK][64];

    const int lane = threadIdx.x & 63;
    const int w    = threadIdx.x >> 6;
    const int bh   = blockIdx.x >> 4;
    const int col  = ((blockIdx.x & 15) << 6) + lane;

    const float* p = att + (size_t)bh * SS * SS + (size_t)(w * 256) * SS + col;

    float a[KK];
#pragma unroll
    for (int k = 0; k < KK; ++k) a[k] = NEG_FLT_MAX;

    for (int j = 0; j < 256; j += 16) {
        const float* q = p + (size_t)j * SS;
        float v[16];
#pragma unroll
        for (int r = 0; r < 16; ++r) v[r] = q[(size_t)r * SS];
#pragma unroll
        for (int r = 0; r < 16; ++r) topk_insert(a, v[r]);
    }

#pragma unroll
    for (int k = 0; k < KK; ++k) lds[w][k][lane] = a[k];
    __syncthreads();

    if (w == 0) {
#pragma unroll
        for (int c = 1; c < 4; ++c)
#pragma unroll
            for (int k = 0; k < KK; ++k)
                topk_insert(a, lds[c][k][lane]);
        const int b = bh >> 4;
        const int h = bh & (HH - 1);
        float* o = feats + ((size_t)(b * SS + col) * HH + h) * KK;
#pragma unroll
        for (int k = 0; k < KK; ++k) o[k] = a[k];
    }
}

// Tiny linear layer: one thread per (b, s). W cached in LDS (broadcast reads).
__global__ __launch_bounds__(256) void linear_kernel(
        const float* __restrict__ feats, const float* __restrict__ W,
        const float* __restrict__ bias, float* __restrict__ out) {
    __shared__ float sW[NL * FF];
    __shared__ float sb[NL];
    for (int i = threadIdx.x; i < NL * FF; i += 256) sW[i] = W[i];
    if (threadIdx.x < NL) sb[threadIdx.x] = bias[threadIdx.x];
    __syncthreads();

    const int t = blockIdx.x * 256 + threadIdx.x;   // 0 .. B*S-1

    const float4* f4 = (const float4*)(feats + (size_t)t * FF);
    float acc[NL];
#pragma unroll
    for (int l = 0; l < NL; ++l) acc[l] = sb[l];

#pragma unroll 4
    for (int i = 0; i < FF / 4; ++i) {
        const float4 v = f4[i];
#pragma unroll
        for (int l = 0; l < NL; ++l) {
            const float* w = &sW[l * FF + i * 4];
            acc[l] += v.x * w[0] + v.y * w[1] + v.z * w[2] + v.w * w[3];
        }
    }

    float4* o4 = (float4*)(out + (size_t)t * NL);
    o4[0] = make_float4(acc[0], acc[1], acc[2], acc[3]);
    o4[1] = make_float4(acc[4], acc[5], acc[6], acc[7]);
}

extern "C" void kernel_launch(void* const* d_in, const int* in_sizes, int n_in,
                              void* d_out, int out_size, void* d_ws, size_t ws_size,
                              hipStream_t stream) {
    const float* att  = (const float*)d_in[0];   // (B,H,S,S) fp32
    const float* W    = (const float*)d_in[1];   // (8,160)   fp32
    const float* bias = (const float*)d_in[2];   // (8,)      fp32
    float* out = (float*)d_out;                  // (B,S,8)   fp32

    if (ws_size >= (size_t)TOTAL_WS_BYTES) {
        float* partial = (float*)d_ws;
        float* feats   = (float*)d_ws + FEATS_OFF_F;
        topk_partial_kernel<<<BB * HH * NQ, 256, 0, stream>>>(att, partial);
        topk_merge_kernel<<<(BB * HH * SS) / 256, 256, 0, stream>>>(partial, feats);
        linear_kernel<<<(BB * SS) / 256, 256, 0, stream>>>(feats, W, bias, out);
    } else {
        float* feats = (float*)d_ws;             // needs 5.25 MB
        topk_kernel_fb<<<(BB * HH * SS) / 64, 256, 0, stream>>>(att, feats);
        linear_kernel<<<(BB * SS) / 256, 256, 0, stream>>>(feats, W, bias, out);
    }
}